// Round 4
// baseline (507.552 us; speedup 1.0000x reference)
//
#include <hip/hip_runtime.h>
#include <math.h>

typedef unsigned short u16;
typedef unsigned int u32;
typedef unsigned short us4 __attribute__((ext_vector_type(4)));
typedef unsigned short us8 __attribute__((ext_vector_type(8)));
typedef short bh8 __attribute__((ext_vector_type(8)));   // 8 bf16 (guide §3)
typedef float f4 __attribute__((ext_vector_type(4)));

#define MFMA16(a, b, c) __builtin_amdgcn_mfma_f32_16x16x32_bf16((a), (b), (c), 0, 0, 0)

__device__ __forceinline__ u16 f2bf(float f) {
  unsigned u = __builtin_bit_cast(unsigned, f);
  u += 0x7FFFu + ((u >> 16) & 1u);   // RNE
  return (u16)(u >> 16);
}
__device__ __forceinline__ float bf2f(u16 h) {
  return __builtin_bit_cast(float, ((unsigned)h) << 16);
}
// gfx950 packed f32->bf16 RNE convert (T12 recipe: no builtin, inline asm)
__device__ __forceinline__ u32 cvt_pk_bf16(float lo, float hi) {
  u32 r;
  asm("v_cvt_pk_bf16_f32 %0, %1, %2" : "=v"(r) : "v"(lo), "v"(hi));
  return r;
}
__device__ __forceinline__ bh8 ld8(const u16* p) {
  return __builtin_bit_cast(bh8, *(const us8*)p);
}
// async global->LDS, 16B per lane. LDS dest = wave-uniform base + lane*16.
__device__ __forceinline__ void gl_lds16(const u16* g, u16* l) {
  __builtin_amdgcn_global_load_lds(
      (const __attribute__((address_space(1))) u32*)g,
      (__attribute__((address_space(3))) u32*)l, 16, 0, 0);
}

// ---------------- fused fp32 -> bf16 (x, Wq, Wkv, Wo) ----------------
__global__ __launch_bounds__(256) void conv4_kernel(const float* __restrict__ x,
                                                    const float* __restrict__ wq,
                                                    const float* __restrict__ wkv,
                                                    const float* __restrict__ wo,
                                                    u16* __restrict__ xb,
                                                    u16* __restrict__ wqb,
                                                    u16* __restrict__ wkvb,
                                                    u16* __restrict__ wob) {
  int i = blockIdx.x * 256 + threadIdx.x;
  const float* in;
  u16* out;
  int j;
  if (i < 2097152) { in = x; out = xb; j = i; }
  else if (i < 3145728) { in = wq; out = wqb; j = i - 2097152; }
  else if (i < 3670016) { in = wkv; out = wkvb; j = i - 3145728; }
  else { in = wo; out = wob; j = i - 3670016; }
  float4 v = ((const float4*)in)[j];
  us4 o;
  o[0] = f2bf(v.x); o[1] = f2bf(v.y); o[2] = f2bf(v.z); o[3] = f2bf(v.w);
  *(us4*)(out + (size_t)j * 4) = o;
}

// ---------------- fused QKV projection + RoPE epilogue ----------------
// R12: rope_kernel fused here. Block col range = exactly one head (128
// cols). RoPE pair (d, d+64): d<64 lives in wn=0 waves, d+64 in wn=1 at
// identical (nt,lr,mt,lq,r). Epilogue: wn=1 dumps a2=acc+bias into the
// dead 32KB A/B staging LDS (f32 [128 rows][64 d]); barrier; wn=0 reads
// partner, sincosf-rotates (same angle math as old rope_kernel), writes
// BOTH halves. a1/a2 are pre-bf16-rounding f32 now (closer to f32 ref).
// Q side scaled by 128^-0.5*log2(e) so attn softmax uses raw exp2.
__global__ __launch_bounds__(256) void gemm_qkv(const u16* __restrict__ A,
                                                const u16* __restrict__ W,
                                                const float* __restrict__ bq,
                                                const float* __restrict__ bkv,
                                                u16* __restrict__ qout,
                                                u16* __restrict__ kvout) {
  const int K = 2048;
  __shared__ __align__(16) u16 ldsAB[2][128][64];   // [0]=A, [1]=B; 32 KB
  const int tid = threadIdx.x;
  const int w = tid >> 6, l = tid & 63, lr = l & 15, lq = l >> 4;
  const int wm = w >> 1, wn = w & 1;
  const int rowBase = blockIdx.y * 128, colBase = blockIdx.x * 128;
  const int srow = l >> 3;
  const int scol = ((l & 7) ^ srow) * 8;

  f4 acc[4][4];
#pragma unroll
  for (int i = 0; i < 4; i++)
#pragma unroll
    for (int j = 0; j < 4; j++) acc[i][j] = (f4)0.0f;

  for (int k0 = 0; k0 < K; k0 += 64) {
    __syncthreads();
#pragma unroll
    for (int i = 0; i < 4; i++) {
      int r0 = w * 32 + i * 8;
      int grow = r0 + srow;
      gl_lds16(A + (size_t)(rowBase + grow) * K + k0 + scol, &ldsAB[0][r0][0]);
      gl_lds16(W + (size_t)(colBase + grow) * K + k0 + scol, &ldsAB[1][r0][0]);
    }
    __syncthreads();
#pragma unroll
    for (int kk = 0; kk < 64; kk += 32) {
      bh8 af[4], bf[4];
#pragma unroll
      for (int t = 0; t < 4; t++) {
        int c = ((((kk >> 3) + lq) ^ (lr & 7)) * 8);
        af[t] = ld8(&ldsAB[0][wm * 64 + t * 16 + lr][c]);
        bf[t] = ld8(&ldsAB[1][wn * 64 + t * 16 + lr][c]);
      }
#pragma unroll
      for (int mt = 0; mt < 4; mt++)
#pragma unroll
        for (int nt = 0; nt < 4; nt++)
          acc[mt][nt] = MFMA16(af[mt], bf[nt], acc[mt][nt]);
    }
  }

  const bool isv = (colBase >= 2560);   // v-heads: no rope
  if (!isv) {
    const float sc = (colBase < 2048) ? 0.12751879522655792f : 1.0f;
    float* scr = (float*)&ldsAB[0][0][0];   // 8192 f32 = 32 KB scratch
    __syncthreads();   // main-loop LDS reads fully retired
    if (wn == 1) {
      // store a2 = acc + bias at [row128][d0 64]
#pragma unroll
      for (int nt = 0; nt < 4; nt++) {
        int col = colBase + 64 + nt * 16 + lr;
        float bv = (col < 2048) ? bq[col] : bkv[col - 2048];
#pragma unroll
        for (int mt = 0; mt < 4; mt++)
#pragma unroll
          for (int r = 0; r < 4; r++)
            scr[(wm * 64 + mt * 16 + 4 * lq + r) * 64 + nt * 16 + lr] =
                acc[mt][nt][r] + bv;
      }
    }
    __syncthreads();
    if (wn == 0) {
#pragma unroll
      for (int nt = 0; nt < 4; nt++) {
        int col = colBase + nt * 16 + lr;   // d0 = nt*16+lr in [0,64)
        float bv = (col < 2048) ? bq[col] : bkv[col - 2048];
        int i = nt * 16 + lr;
        float invf = exp2f(-(float)i * 0.20762050593046012f);
#pragma unroll
        for (int mt = 0; mt < 4; mt++) {
#pragma unroll
          for (int r = 0; r < 4; r++) {
            int row = rowBase + wm * 64 + mt * 16 + 4 * lq + r;
            int s = row & 2047;
            float a1 = acc[mt][nt][r] + bv;
            float a2 = scr[(wm * 64 + mt * 16 + 4 * lq + r) * 64 + i];
            float sn, cs;
            sincosf((float)s * invf, &sn, &cs);
            float o0 = (a1 * cs - a2 * sn) * sc;
            float o1 = (a2 * cs + a1 * sn) * sc;
            if (col < 2048) {
              qout[(size_t)row * 2048 + col] = f2bf(o0);
              qout[(size_t)row * 2048 + col + 64] = f2bf(o1);
            } else {
              kvout[(size_t)row * 1024 + col - 2048] = f2bf(o0);
              kvout[(size_t)row * 1024 + col - 2048 + 64] = f2bf(o1);
            }
          }
        }
      }
    }
  } else {
    // v-heads: plain biased write
#pragma unroll
    for (int mt = 0; mt < 4; mt++) {
#pragma unroll
      for (int nt = 0; nt < 4; nt++) {
        int col = colBase + wn * 64 + nt * 16 + lr;
        float bv = bkv[col - 2048];
#pragma unroll
        for (int r = 0; r < 4; r++) {
          int row = rowBase + wm * 64 + mt * 16 + 4 * lq + r;
          kvout[(size_t)row * 1024 + col - 2048] = f2bf(acc[mt][nt][r] + bv);
        }
      }
    }
  }
}

// ---------------- O projection: C = A * W^T (fp32 out) ----------------
__global__ __launch_bounds__(256) void gemm_bt(const u16* __restrict__ A,
                                               const u16* __restrict__ W,
                                               float* __restrict__ outp,
                                               int M, int N, int K) {
  __shared__ __align__(16) u16 lA[128][64];
  __shared__ __align__(16) u16 lB[128][64];
  const int tid = threadIdx.x;
  const int w = tid >> 6, l = tid & 63, lr = l & 15, lq = l >> 4;
  const int wm = w >> 1, wn = w & 1;
  const int rowBase = blockIdx.y * 128, colBase = blockIdx.x * 128;
  const int srow = l >> 3;
  const int scol = ((l & 7) ^ srow) * 8;

  f4 acc[4][4];
#pragma unroll
  for (int i = 0; i < 4; i++)
#pragma unroll
    for (int j = 0; j < 4; j++) acc[i][j] = (f4)0.0f;

  for (int k0 = 0; k0 < K; k0 += 64) {
    __syncthreads();
#pragma unroll
    for (int i = 0; i < 4; i++) {
      int r0 = w * 32 + i * 8;
      int grow = r0 + srow;
      gl_lds16(A + (size_t)(rowBase + grow) * K + k0 + scol, &lA[r0][0]);
      gl_lds16(W + (size_t)(colBase + grow) * K + k0 + scol, &lB[r0][0]);
    }
    __syncthreads();
#pragma unroll
    for (int kk = 0; kk < 64; kk += 32) {
      bh8 af[4], bf[4];
#pragma unroll
      for (int t = 0; t < 4; t++) {
        int c = ((((kk >> 3) + lq) ^ (lr & 7)) * 8);
        af[t] = ld8(&lA[wm * 64 + t * 16 + lr][c]);
        bf[t] = ld8(&lB[wn * 64 + t * 16 + lr][c]);
      }
#pragma unroll
      for (int mt = 0; mt < 4; mt++)
#pragma unroll
        for (int nt = 0; nt < 4; nt++)
          acc[mt][nt] = MFMA16(af[mt], bf[nt], acc[mt][nt]);
    }
  }
#pragma unroll
  for (int mt = 0; mt < 4; mt++) {
#pragma unroll
    for (int nt = 0; nt < 4; nt++) {
      int col = colBase + wn * 64 + nt * 16 + lr;
#pragma unroll
      for (int r = 0; r < 4; r++) {
        int row = rowBase + wm * 64 + mt * 16 + 4 * lq + r;
        outp[(size_t)row * N + col] = acc[mt][nt][r];
      }
    }
  }
}

// ---------------- V transpose + key-permute ----------------
__global__ __launch_bounds__(256) void vtrans_kernel(const u16* __restrict__ kvb,
                                                     u16* __restrict__ vtb) {
  __shared__ __align__(16) u16 lT[64][72];
  const int tid = threadIdx.x;
  const int s0 = blockIdx.x * 64, d0 = blockIdx.y * 64;
  const int b = blockIdx.z >> 2, kh = blockIdx.z & 3;
  const u16* src = kvb + ((size_t)b * 2048) * 1024 + 512 + kh * 128;
#pragma unroll
  for (int i = 0; i < 2; i++) {
    int slot = tid + i * 256;
    int sl = slot >> 3, colv = slot & 7;
    *(us8*)&lT[sl][colv * 8] =
        *(const us8*)(src + (size_t)(s0 + sl) * 1024 + d0 + colv * 8);
  }
  __syncthreads();
  u16* dst = vtb + ((size_t)(b * 4 + kh) * 128) * 2048;
#pragma unroll
  for (int i = 0; i < 2; i++) {
    int slot = tid + i * 256;
    int dd = slot >> 3, colv = slot & 7;
    us8 v;
#pragma unroll
    for (int j = 0; j < 8; j++) {
      int p = colv * 8 + j;
      int g = p & 32, q5 = p & 31, lqp = q5 >> 3, jp = q5 & 7;
      int key = g + ((jp < 4) ? (4 * lqp + jp) : (12 + 4 * lqp + jp));
      v[j] = lT[key][dd];
    }
    *(us8*)(dst + (size_t)(d0 + dd) * 2048 + s0 + colv * 8) = v;
  }
}

// ---------------- Flash attention: fixed-base softmax, 32 q/wave ----------
// 128 q-rows/block (4 waves x 32 q), grid 16x32 = 512 blocks.
// R12: EXACT revert to the R1 form (95.6 us, VGPR 120). R1 VALU-shave was
// null, R2 latency-prefetch -3%, R3 in-block split-K spilled (launch_bounds
// reg cap vs 64-reg accumulator). Attn is serial-chain-bound at 2 w/SIMD
// (grid-limited 2 blocks/CU); leave as-is.
__global__ __launch_bounds__(256, 2) void attn_kernel(const u16* __restrict__ qb,
                                                      const u16* __restrict__ kvb,
                                                      const u16* __restrict__ vtb,
                                                      u16* __restrict__ ob) {
  __shared__ __align__(16) u16 lK[64][128];   // [key][d], block c at c^(key&15)
  __shared__ __align__(16) u16 lV[128][64];   // [d][key'], block c at c^(d&7)
  __shared__ float lRed[4][4][16];            // [wave][lq][lr] epilogue scratch
  __shared__ float lBc[4][16];                // [wave][row] epilogue broadcast
  const int tid = threadIdx.x;
  const int w = tid >> 6, l = tid & 63, lr = l & 15, lq = l >> 4;
  const int qt = blockIdx.x, hb = blockIdx.y;
  const int b = hb >> 4, h = hb & 15, kh = h >> 2;
  const u16* kptr = kvb + (size_t)b * 2048 * 1024 + kh * 128;
  const u16* vptr = vtb + (size_t)(b * 4 + kh) * 128 * 2048;
  const int qrow0 = qt * 128 + w * 32;

  const int ksrow = l >> 4;                    // K staging: 4 rows x 16 blk
  const int vsrow = l >> 3;                    // V staging: 8 rows x 8 blk
  const int vscol = ((l & 7) ^ vsrow) * 8;

  // Q B-fragments: lane holds roped Q[q=qrow0+16nt+lr][d=32kt+8lq+j]
  bh8 qf[2][4];
#pragma unroll
  for (int nt = 0; nt < 2; nt++) {
    const u16* qrow =
        qb + (((size_t)(b * 2048 + qrow0 + 16 * nt + lr)) * 16 + h) * 128;
#pragma unroll
    for (int kt = 0; kt < 4; kt++) qf[nt][kt] = ld8(qrow + kt * 32 + 8 * lq);
  }

  f4 accO[2][8];   // O[q=16nt+4lq+r][d=16dt+lr]
#pragma unroll
  for (int nt = 0; nt < 2; nt++)
#pragma unroll
    for (int d = 0; d < 8; d++) accO[nt][d] = (f4)0.0f;
  float lsum[2] = {0.0f, 0.0f};

  for (int t0 = 0; t0 < 2048; t0 += 64) {
    __syncthreads();
#pragma unroll
    for (int i = 0; i < 4; i++) {
      {  // K tile
        int r0 = w * 16 + i * 4;
        int grow = r0 + ksrow;
        int gcol = ((l & 15) ^ (grow & 15)) * 8;
        gl_lds16(kptr + (size_t)(t0 + grow) * 1024 + gcol, &lK[r0][0]);
      }
      {  // V^T tile
        int r0 = w * 32 + i * 8;
        int grow = r0 + vsrow;
        gl_lds16(vptr + (size_t)grow * 2048 + t0 + vscol, &lV[r0][0]);
      }
    }
    __syncthreads();

    // S^T = K Q^T (ak reads shared across both nt)
    f4 accS[4][2];
#pragma unroll
    for (int mt = 0; mt < 4; mt++)
#pragma unroll
      for (int nt = 0; nt < 2; nt++) accS[mt][nt] = (f4)0.0f;
#pragma unroll
    for (int kt = 0; kt < 4; kt++) {
      bh8 ak[4];
#pragma unroll
      for (int mt = 0; mt < 4; mt++)
        ak[mt] = ld8(&lK[16 * mt + lr][((4 * kt + lq) ^ lr) * 8]);
      __builtin_amdgcn_s_setprio(1);
#pragma unroll
      for (int mt = 0; mt < 4; mt++)
#pragma unroll
        for (int nt = 0; nt < 2; nt++)
          accS[mt][nt] = MFMA16(ak[mt], qf[nt][kt], accS[mt][nt]);
      __builtin_amdgcn_s_setprio(0);
    }

    // p = exp2(s); packed-RNE convert (v_cvt_pk_bf16_f32); row-sum accum
    u32 pkl[4][2][2];
#pragma unroll
    for (int nt = 0; nt < 2; nt++)
#pragma unroll
      for (int mt = 0; mt < 4; mt++) {
        float p0 = exp2f(accS[mt][nt][0]);
        float p1 = exp2f(accS[mt][nt][1]);
        float p2 = exp2f(accS[mt][nt][2]);
        float p3 = exp2f(accS[mt][nt][3]);
        lsum[nt] += (p0 + p1) + (p2 + p3);
        pkl[mt][nt][0] = cvt_pk_bf16(p0, p1);
        pkl[mt][nt][1] = cvt_pk_bf16(p2, p3);
      }

    // O += P V (A-frag in-lane; bv reads shared across both nt)
#pragma unroll
    for (int kf = 0; kf < 2; kf++) {
      bh8 ap[2];
#pragma unroll
      for (int nt = 0; nt < 2; nt++)
        ap[nt] = __builtin_bit_cast(
            bh8, (uint4){pkl[2 * kf][nt][0], pkl[2 * kf][nt][1],
                         pkl[2 * kf + 1][nt][0], pkl[2 * kf + 1][nt][1]});
#pragma unroll
      for (int d = 0; d < 8; d++) {
        bh8 bv = ld8(&lV[16 * d + lr][((4 * kf + lq) ^ (lr & 7)) * 8]);
        __builtin_amdgcn_s_setprio(1);
#pragma unroll
        for (int nt = 0; nt < 2; nt++)
          accO[nt][d] = MFMA16(ap[nt], bv, accO[nt][d]);
        __builtin_amdgcn_s_setprio(0);
      }
    }
  }

  // epilogue: reduce row sums across lq, O /= l, write [b][s][h][d] bf16
#pragma unroll
  for (int nt = 0; nt < 2; nt++) {
    lRed[w][lq][lr] = lsum[nt];   // same-wave LDS, in-order per wave
    float lt =
        (lRed[w][0][lr] + lRed[w][1][lr]) + (lRed[w][2][lr] + lRed[w][3][lr]);
    float invl = 1.0f / lt;
    if (lq == 0) lBc[w][lr] = invl;
    float ir[4];
#pragma unroll
    for (int r = 0; r < 4; r++) ir[r] = lBc[w][4 * lq + r];
#pragma unroll
    for (int d = 0; d < 8; d++) {
      int dc = 16 * d + lr;
#pragma unroll
      for (int r = 0; r < 4; r++) {
        int srow = qrow0 + 16 * nt + 4 * lq + r;
        ob[(((size_t)(b * 2048 + srow)) * 16 + h) * 128 + dc] =
            f2bf(accO[nt][d][r] * ir[r]);
      }
    }
  }
}

extern "C" void kernel_launch(void* const* d_in, const int* in_sizes, int n_in,
                              void* d_out, int out_size, void* d_ws, size_t ws_size,
                              hipStream_t stream) {
  const float* x   = (const float*)d_in[0];
  const float* Wq  = (const float*)d_in[1];
  const float* bq  = (const float*)d_in[2];
  const float* Wkv = (const float*)d_in[3];
  const float* bkv = (const float*)d_in[4];
  const float* Wo  = (const float*)d_in[5];
  float* out = (float*)d_out;

  u16* xb    = (u16*)d_ws;          // 4096x2048
  u16* wqb   = xb + 8388608;        // 2048x2048  (wkvb contiguous -> fused W)
  u16* wkvb  = wqb + 4194304;       // 1024x2048
  u16* wob   = wkvb + 2097152;      // 2048x2048
  u16* qbf   = wob + 4194304;       // [b][s][16][128] (roped in gemm_qkv)
  u16* kvbf  = qbf + 8388608;       // [b][s][1024]   (k roped in gemm_qkv)
  u16* vtb   = kvbf + 4194304;      // [b][kh][128][2048] (key-permuted)
  u16* attnb = vtb + 2097152;       // [b][s][16][128]

  conv4_kernel<<<18432, 256, 0, stream>>>(x, Wq, Wkv, Wo, xb, wqb, wkvb, wob);
  gemm_qkv<<<dim3(24, 32), 256, 0, stream>>>(xb, wqb, bq, bkv, qbf, kvbf);
  vtrans_kernel<<<dim3(32, 2, 8), 256, 0, stream>>>(kvbf, vtb);
  attn_kernel<<<dim3(16, 32), 256, 0, stream>>>(qbf, kvbf, vtb, attnb);
  gemm_bt<<<dim3(16, 32), 256, 0, stream>>>(attnb, wob, out, 4096, 2048, 2048);
}

// Round 5
// 504.071 us; speedup vs baseline: 1.0069x; 1.0069x over previous
//
#include <hip/hip_runtime.h>
#include <math.h>

typedef unsigned short u16;
typedef unsigned int u32;
typedef unsigned short us4 __attribute__((ext_vector_type(4)));
typedef unsigned short us8 __attribute__((ext_vector_type(8)));
typedef short bh8 __attribute__((ext_vector_type(8)));   // 8 bf16 (guide §3)
typedef float f4 __attribute__((ext_vector_type(4)));

#define MFMA16(a, b, c) __builtin_amdgcn_mfma_f32_16x16x32_bf16((a), (b), (c), 0, 0, 0)

__device__ __forceinline__ u16 f2bf(float f) {
  unsigned u = __builtin_bit_cast(unsigned, f);
  u += 0x7FFFu + ((u >> 16) & 1u);   // RNE
  return (u16)(u >> 16);
}
__device__ __forceinline__ float bf2f(u16 h) {
  return __builtin_bit_cast(float, ((unsigned)h) << 16);
}
// gfx950 packed f32->bf16 RNE convert (T12 recipe: no builtin, inline asm)
__device__ __forceinline__ u32 cvt_pk_bf16(float lo, float hi) {
  u32 r;
  asm("v_cvt_pk_bf16_f32 %0, %1, %2" : "=v"(r) : "v"(lo), "v"(hi));
  return r;
}
__device__ __forceinline__ bh8 ld8(const u16* p) {
  return __builtin_bit_cast(bh8, *(const us8*)p);
}
// async global->LDS, 16B per lane. LDS dest = wave-uniform base + lane*16.
__device__ __forceinline__ void gl_lds16(const u16* g, u16* l) {
  __builtin_amdgcn_global_load_lds(
      (const __attribute__((address_space(1))) u32*)g,
      (__attribute__((address_space(3))) u32*)l, 16, 0, 0);
}

// ---------------- fused fp32 -> bf16 (x, Wq, Wkv, Wo) ----------------
__global__ __launch_bounds__(256) void conv4_kernel(const float* __restrict__ x,
                                                    const float* __restrict__ wq,
                                                    const float* __restrict__ wkv,
                                                    const float* __restrict__ wo,
                                                    u16* __restrict__ xb,
                                                    u16* __restrict__ wqb,
                                                    u16* __restrict__ wkvb,
                                                    u16* __restrict__ wob) {
  int i = blockIdx.x * 256 + threadIdx.x;
  const float* in;
  u16* out;
  int j;
  if (i < 2097152) { in = x; out = xb; j = i; }
  else if (i < 3145728) { in = wq; out = wqb; j = i - 2097152; }
  else if (i < 3670016) { in = wkv; out = wkvb; j = i - 3145728; }
  else { in = wo; out = wob; j = i - 3670016; }
  float4 v = ((const float4*)in)[j];
  us4 o;
  o[0] = f2bf(v.x); o[1] = f2bf(v.y); o[2] = f2bf(v.z); o[3] = f2bf(v.w);
  *(us4*)(out + (size_t)j * 4) = o;
}

// ---------------- fused QKV projection (R1-exact; NO epilogue fattening:
// any extra live state here spills the 64-reg accumulator — R3/R4) -------
__global__ __launch_bounds__(256) void gemm_qkv(const u16* __restrict__ A,
                                                const u16* __restrict__ W,
                                                const float* __restrict__ bq,
                                                const float* __restrict__ bkv,
                                                u16* __restrict__ qout,
                                                u16* __restrict__ kvout) {
  const int K = 2048;
  __shared__ __align__(16) u16 lA[128][64];
  __shared__ __align__(16) u16 lB[128][64];
  const int tid = threadIdx.x;
  const int w = tid >> 6, l = tid & 63, lr = l & 15, lq = l >> 4;
  const int wm = w >> 1, wn = w & 1;
  const int rowBase = blockIdx.y * 128, colBase = blockIdx.x * 128;
  const int srow = l >> 3;
  const int scol = ((l & 7) ^ srow) * 8;

  f4 acc[4][4];
#pragma unroll
  for (int i = 0; i < 4; i++)
#pragma unroll
    for (int j = 0; j < 4; j++) acc[i][j] = (f4)0.0f;

  for (int k0 = 0; k0 < K; k0 += 64) {
    __syncthreads();
#pragma unroll
    for (int i = 0; i < 4; i++) {
      int r0 = w * 32 + i * 8;
      int grow = r0 + srow;
      gl_lds16(A + (size_t)(rowBase + grow) * K + k0 + scol, &lA[r0][0]);
      gl_lds16(W + (size_t)(colBase + grow) * K + k0 + scol, &lB[r0][0]);
    }
    __syncthreads();
#pragma unroll
    for (int kk = 0; kk < 64; kk += 32) {
      bh8 af[4], bf[4];
#pragma unroll
      for (int t = 0; t < 4; t++) {
        int c = ((((kk >> 3) + lq) ^ (lr & 7)) * 8);
        af[t] = ld8(&lA[wm * 64 + t * 16 + lr][c]);
        bf[t] = ld8(&lB[wn * 64 + t * 16 + lr][c]);
      }
#pragma unroll
      for (int mt = 0; mt < 4; mt++)
#pragma unroll
        for (int nt = 0; nt < 4; nt++)
          acc[mt][nt] = MFMA16(af[mt], bf[nt], acc[mt][nt]);
    }
  }
#pragma unroll
  for (int mt = 0; mt < 4; mt++) {
#pragma unroll
    for (int nt = 0; nt < 4; nt++) {
      int col = colBase + wn * 64 + nt * 16 + lr;
      float bv = (col < 2048) ? bq[col] : bkv[col - 2048];
#pragma unroll
      for (int r = 0; r < 4; r++) {
        int row = rowBase + wm * 64 + mt * 16 + 4 * lq + r;
        float v = acc[mt][nt][r] + bv;
        if (col < 2048)
          qout[(size_t)row * 2048 + col] = f2bf(v);
        else
          kvout[(size_t)row * 1024 + col - 2048] = f2bf(v);
      }
    }
  }
}

// ---------------- O projection: C = A * W^T (fp32 out) ----------------
__global__ __launch_bounds__(256) void gemm_bt(const u16* __restrict__ A,
                                               const u16* __restrict__ W,
                                               float* __restrict__ outp,
                                               int M, int N, int K) {
  __shared__ __align__(16) u16 lA[128][64];
  __shared__ __align__(16) u16 lB[128][64];
  const int tid = threadIdx.x;
  const int w = tid >> 6, l = tid & 63, lr = l & 15, lq = l >> 4;
  const int wm = w >> 1, wn = w & 1;
  const int rowBase = blockIdx.y * 128, colBase = blockIdx.x * 128;
  const int srow = l >> 3;
  const int scol = ((l & 7) ^ srow) * 8;

  f4 acc[4][4];
#pragma unroll
  for (int i = 0; i < 4; i++)
#pragma unroll
    for (int j = 0; j < 4; j++) acc[i][j] = (f4)0.0f;

  for (int k0 = 0; k0 < K; k0 += 64) {
    __syncthreads();
#pragma unroll
    for (int i = 0; i < 4; i++) {
      int r0 = w * 32 + i * 8;
      int grow = r0 + srow;
      gl_lds16(A + (size_t)(rowBase + grow) * K + k0 + scol, &lA[r0][0]);
      gl_lds16(W + (size_t)(colBase + grow) * K + k0 + scol, &lB[r0][0]);
    }
    __syncthreads();
#pragma unroll
    for (int kk = 0; kk < 64; kk += 32) {
      bh8 af[4], bf[4];
#pragma unroll
      for (int t = 0; t < 4; t++) {
        int c = ((((kk >> 3) + lq) ^ (lr & 7)) * 8);
        af[t] = ld8(&lA[wm * 64 + t * 16 + lr][c]);
        bf[t] = ld8(&lB[wn * 64 + t * 16 + lr][c]);
      }
#pragma unroll
      for (int mt = 0; mt < 4; mt++)
#pragma unroll
        for (int nt = 0; nt < 4; nt++)
          acc[mt][nt] = MFMA16(af[mt], bf[nt], acc[mt][nt]);
    }
  }
#pragma unroll
  for (int mt = 0; mt < 4; mt++) {
#pragma unroll
    for (int nt = 0; nt < 4; nt++) {
      int col = colBase + wn * 64 + nt * 16 + lr;
#pragma unroll
      for (int r = 0; r < 4; r++) {
        int row = rowBase + wm * 64 + mt * 16 + 4 * lq + r;
        outp[(size_t)row * N + col] = acc[mt][nt][r];
      }
    }
  }
}

// ---------------- RoPE in-place on bf16 q and k (R5-exact) ----------------
// Q scaled by 1/sqrt(128) * log2(e): softmax then uses raw exp2.
__global__ __launch_bounds__(256) void rope_kernel(u16* __restrict__ qb,
                                                   u16* __restrict__ kvb) {
  const int NQ = 2 * 2048 * 16 * 64;
  int idx = blockIdx.x * 256 + threadIdx.x;
  u16 *p0, *p1;
  int i, s;
  float sc;
  if (idx < NQ) {
    i = idx & 63;
    int h = (idx >> 6) & 15;
    s = (idx >> 10) & 2047;
    int b = idx >> 21;
    size_t base = (((size_t)(b * 2048 + s)) * 16 + h) * 128;
    p0 = qb + base + i;
    p1 = qb + base + 64 + i;
    sc = 0.12751879522655792f;  // 128^-0.5 * log2(e)
  } else {
    int j = idx - NQ;
    i = j & 63;
    int kh = (j >> 6) & 3;
    s = (j >> 8) & 2047;
    int b = j >> 19;
    size_t base = ((size_t)(b * 2048 + s)) * 1024 + kh * 128;
    p0 = kvb + base + i;
    p1 = kvb + base + 64 + i;
    sc = 1.0f;
  }
  float invf = exp2f(-(float)i * 0.20762050593046012f);
  float ang = (float)s * invf;
  float sn, cs;
  sincosf(ang, &sn, &cs);
  float a1 = bf2f(*p0), a2 = bf2f(*p1);
  *p0 = f2bf((a1 * cs - a2 * sn) * sc);
  *p1 = f2bf((a2 * cs + a1 * sn) * sc);
}

// ---------------- V transpose + key-permute ----------------
__global__ __launch_bounds__(256) void vtrans_kernel(const u16* __restrict__ kvb,
                                                     u16* __restrict__ vtb) {
  __shared__ __align__(16) u16 lT[64][72];
  const int tid = threadIdx.x;
  const int s0 = blockIdx.x * 64, d0 = blockIdx.y * 64;
  const int b = blockIdx.z >> 2, kh = blockIdx.z & 3;
  const u16* src = kvb + ((size_t)b * 2048) * 1024 + 512 + kh * 128;
#pragma unroll
  for (int i = 0; i < 2; i++) {
    int slot = tid + i * 256;
    int sl = slot >> 3, colv = slot & 7;
    *(us8*)&lT[sl][colv * 8] =
        *(const us8*)(src + (size_t)(s0 + sl) * 1024 + d0 + colv * 8);
  }
  __syncthreads();
  u16* dst = vtb + ((size_t)(b * 4 + kh) * 128) * 2048;
#pragma unroll
  for (int i = 0; i < 2; i++) {
    int slot = tid + i * 256;
    int dd = slot >> 3, colv = slot & 7;
    us8 v;
#pragma unroll
    for (int j = 0; j < 8; j++) {
      int p = colv * 8 + j;
      int g = p & 32, q5 = p & 31, lqp = q5 >> 3, jp = q5 & 7;
      int key = g + ((jp < 4) ? (4 * lqp + jp) : (12 + 4 * lqp + jp));
      v[j] = lT[key][dd];
    }
    *(us8*)(dst + (size_t)(d0 + dd) * 2048 + s0 + colv * 8) = v;
  }
}

// ---------------- Flash attention, split-K across blocks (R13) ------------
// R3's occupancy theory, tested properly this time: grid 16x32x2; block z
// does keys [1024z, 1024z+1024). 256 threads (natural VGPR 120) with
// __launch_bounds__(256,4): cap 128 >= 120 -> no spill (R3 failed because
// (512,4) capped at 64). LDS 34 KB -> 4 blocks/CU -> 16 waves/CU, 4/SIMD.
// Fixed-base softmax => partials add: write un-normalized accO (f32) and
// per-row denom partial lt; attn_combine does (O0+O1)/(l0+l1) -> bf16.
__global__ __launch_bounds__(256, 4) void attn_split(const u16* __restrict__ qb,
                                                     const u16* __restrict__ kvb,
                                                     const u16* __restrict__ vtb,
                                                     float* __restrict__ opart,
                                                     float* __restrict__ lpart) {
  __shared__ __align__(16) u16 lK[64][128];   // [key][d], block c at c^(key&15)
  __shared__ __align__(16) u16 lV[128][64];   // [d][key'], block c at c^(d&7)
  __shared__ float lRed[4][4][16];            // [wave][lq][lr] epilogue scratch
  const int tid = threadIdx.x;
  const int w = tid >> 6, l = tid & 63, lr = l & 15, lq = l >> 4;
  const int qt = blockIdx.x, hb = blockIdx.y, z = blockIdx.z;
  const int b = hb >> 4, h = hb & 15, kh = h >> 2;
  const u16* kptr = kvb + (size_t)b * 2048 * 1024 + kh * 128;
  const u16* vptr = vtb + (size_t)(b * 4 + kh) * 128 * 2048;
  const int qrow0 = qt * 128 + w * 32;
  const size_t ZO = (size_t)2 * 2048 * 16 * 128;   // opart floats per z
  const size_t ZL = (size_t)2 * 2048 * 16;         // lpart floats per z

  const int ksrow = l >> 4;                    // K staging: 4 rows x 16 blk
  const int vsrow = l >> 3;                    // V staging: 8 rows x 8 blk
  const int vscol = ((l & 7) ^ vsrow) * 8;

  // Q B-fragments: lane holds roped Q[q=qrow0+16nt+lr][d=32kt+8lq+j]
  bh8 qf[2][4];
#pragma unroll
  for (int nt = 0; nt < 2; nt++) {
    const u16* qrow =
        qb + (((size_t)(b * 2048 + qrow0 + 16 * nt + lr)) * 16 + h) * 128;
#pragma unroll
    for (int kt = 0; kt < 4; kt++) qf[nt][kt] = ld8(qrow + kt * 32 + 8 * lq);
  }

  f4 accO[2][8];   // O[q=16nt+4lq+r][d=16dt+lr]
#pragma unroll
  for (int nt = 0; nt < 2; nt++)
#pragma unroll
    for (int d = 0; d < 8; d++) accO[nt][d] = (f4)0.0f;
  float lsum[2] = {0.0f, 0.0f};

  for (int t0 = z * 1024; t0 < z * 1024 + 1024; t0 += 64) {
    __syncthreads();
#pragma unroll
    for (int i = 0; i < 4; i++) {
      {  // K tile
        int r0 = w * 16 + i * 4;
        int grow = r0 + ksrow;
        int gcol = ((l & 15) ^ (grow & 15)) * 8;
        gl_lds16(kptr + (size_t)(t0 + grow) * 1024 + gcol, &lK[r0][0]);
      }
      {  // V^T tile
        int r0 = w * 32 + i * 8;
        int grow = r0 + vsrow;
        gl_lds16(vptr + (size_t)grow * 2048 + t0 + vscol, &lV[r0][0]);
      }
    }
    __syncthreads();

    // S^T = K Q^T (ak reads shared across both nt)
    f4 accS[4][2];
#pragma unroll
    for (int mt = 0; mt < 4; mt++)
#pragma unroll
      for (int nt = 0; nt < 2; nt++) accS[mt][nt] = (f4)0.0f;
#pragma unroll
    for (int kt = 0; kt < 4; kt++) {
      bh8 ak[4];
#pragma unroll
      for (int mt = 0; mt < 4; mt++)
        ak[mt] = ld8(&lK[16 * mt + lr][((4 * kt + lq) ^ lr) * 8]);
      __builtin_amdgcn_s_setprio(1);
#pragma unroll
      for (int mt = 0; mt < 4; mt++)
#pragma unroll
        for (int nt = 0; nt < 2; nt++)
          accS[mt][nt] = MFMA16(ak[mt], qf[nt][kt], accS[mt][nt]);
      __builtin_amdgcn_s_setprio(0);
    }

    // p = exp2(s); packed-RNE convert (v_cvt_pk_bf16_f32); row-sum accum
    u32 pkl[4][2][2];
#pragma unroll
    for (int nt = 0; nt < 2; nt++)
#pragma unroll
      for (int mt = 0; mt < 4; mt++) {
        float p0 = exp2f(accS[mt][nt][0]);
        float p1 = exp2f(accS[mt][nt][1]);
        float p2 = exp2f(accS[mt][nt][2]);
        float p3 = exp2f(accS[mt][nt][3]);
        lsum[nt] += (p0 + p1) + (p2 + p3);
        pkl[mt][nt][0] = cvt_pk_bf16(p0, p1);
        pkl[mt][nt][1] = cvt_pk_bf16(p2, p3);
      }

    // O += P V (A-frag in-lane; bv reads shared across both nt)
#pragma unroll
    for (int kf = 0; kf < 2; kf++) {
      bh8 ap[2];
#pragma unroll
      for (int nt = 0; nt < 2; nt++)
        ap[nt] = __builtin_bit_cast(
            bh8, (uint4){pkl[2 * kf][nt][0], pkl[2 * kf][nt][1],
                         pkl[2 * kf + 1][nt][0], pkl[2 * kf + 1][nt][1]});
#pragma unroll
      for (int d = 0; d < 8; d++) {
        bh8 bv = ld8(&lV[16 * d + lr][((4 * kf + lq) ^ (lr & 7)) * 8]);
        __builtin_amdgcn_s_setprio(1);
#pragma unroll
        for (int nt = 0; nt < 2; nt++)
          accO[nt][d] = MFMA16(ap[nt], bv, accO[nt][d]);
        __builtin_amdgcn_s_setprio(0);
      }
    }
  }

  // epilogue: per-block denom partial + raw accO f32 partials
#pragma unroll
  for (int nt = 0; nt < 2; nt++) {
    lRed[w][lq][lr] = lsum[nt];   // same-wave LDS, in-order per wave
    float lt =
        (lRed[w][0][lr] + lRed[w][1][lr]) + (lRed[w][2][lr] + lRed[w][3][lr]);
    if (lq == 0)
      lpart[z * ZL + ((size_t)(b * 2048 + qrow0 + 16 * nt + lr)) * 16 + h] = lt;
#pragma unroll
    for (int d = 0; d < 8; d++) {
      int dc = 16 * d + lr;
#pragma unroll
      for (int r = 0; r < 4; r++) {
        int srow = qrow0 + 16 * nt + 4 * lq + r;
        opart[z * ZO + (((size_t)(b * 2048 + srow)) * 16 + h) * 128 + dc] =
            accO[nt][d][r];
      }
    }
  }
}

// combine: ob = (O0+O1) / (l0+l1), bf16
__global__ __launch_bounds__(256) void attn_combine(const float* __restrict__ opart,
                                                    const float* __restrict__ lpart,
                                                    u16* __restrict__ ob) {
  const size_t ZO = (size_t)2 * 2048 * 16 * 128;
  const size_t ZL = (size_t)2 * 2048 * 16;
  int t = blockIdx.x * 256 + threadIdx.x;   // [0, 2*2048*16*32)
  int d4 = t & 31;
  int bsh = t >> 5;
  size_t base = (size_t)bsh * 128 + d4 * 4;
  float4 o0 = *(const float4*)(opart + base);
  float4 o1 = *(const float4*)(opart + ZO + base);
  float inv = 1.0f / (lpart[bsh] + lpart[ZL + bsh]);
  us4 o;
  o[0] = f2bf((o0.x + o1.x) * inv);
  o[1] = f2bf((o0.y + o1.y) * inv);
  o[2] = f2bf((o0.z + o1.z) * inv);
  o[3] = f2bf((o0.w + o1.w) * inv);
  *(us4*)(ob + base) = o;
}

// ---------------- single-pass attention (R1-exact fallback) ----------------
__global__ __launch_bounds__(256, 2) void attn_kernel(const u16* __restrict__ qb,
                                                      const u16* __restrict__ kvb,
                                                      const u16* __restrict__ vtb,
                                                      u16* __restrict__ ob) {
  __shared__ __align__(16) u16 lK[64][128];
  __shared__ __align__(16) u16 lV[128][64];
  __shared__ float lRed[4][4][16];
  __shared__ float lBc[4][16];
  const int tid = threadIdx.x;
  const int w = tid >> 6, l = tid & 63, lr = l & 15, lq = l >> 4;
  const int qt = blockIdx.x, hb = blockIdx.y;
  const int b = hb >> 4, h = hb & 15, kh = h >> 2;
  const u16* kptr = kvb + (size_t)b * 2048 * 1024 + kh * 128;
  const u16* vptr = vtb + (size_t)(b * 4 + kh) * 128 * 2048;
  const int qrow0 = qt * 128 + w * 32;

  const int ksrow = l >> 4;
  const int vsrow = l >> 3;
  const int vscol = ((l & 7) ^ vsrow) * 8;

  bh8 qf[2][4];
#pragma unroll
  for (int nt = 0; nt < 2; nt++) {
    const u16* qrow =
        qb + (((size_t)(b * 2048 + qrow0 + 16 * nt + lr)) * 16 + h) * 128;
#pragma unroll
    for (int kt = 0; kt < 4; kt++) qf[nt][kt] = ld8(qrow + kt * 32 + 8 * lq);
  }

  f4 accO[2][8];
#pragma unroll
  for (int nt = 0; nt < 2; nt++)
#pragma unroll
    for (int d = 0; d < 8; d++) accO[nt][d] = (f4)0.0f;
  float lsum[2] = {0.0f, 0.0f};

  for (int t0 = 0; t0 < 2048; t0 += 64) {
    __syncthreads();
#pragma unroll
    for (int i = 0; i < 4; i++) {
      {
        int r0 = w * 16 + i * 4;
        int grow = r0 + ksrow;
        int gcol = ((l & 15) ^ (grow & 15)) * 8;
        gl_lds16(kptr + (size_t)(t0 + grow) * 1024 + gcol, &lK[r0][0]);
      }
      {
        int r0 = w * 32 + i * 8;
        int grow = r0 + vsrow;
        gl_lds16(vptr + (size_t)grow * 2048 + t0 + vscol, &lV[r0][0]);
      }
    }
    __syncthreads();

    f4 accS[4][2];
#pragma unroll
    for (int mt = 0; mt < 4; mt++)
#pragma unroll
      for (int nt = 0; nt < 2; nt++) accS[mt][nt] = (f4)0.0f;
#pragma unroll
    for (int kt = 0; kt < 4; kt++) {
      bh8 ak[4];
#pragma unroll
      for (int mt = 0; mt < 4; mt++)
        ak[mt] = ld8(&lK[16 * mt + lr][((4 * kt + lq) ^ lr) * 8]);
      __builtin_amdgcn_s_setprio(1);
#pragma unroll
      for (int mt = 0; mt < 4; mt++)
#pragma unroll
        for (int nt = 0; nt < 2; nt++)
          accS[mt][nt] = MFMA16(ak[mt], qf[nt][kt], accS[mt][nt]);
      __builtin_amdgcn_s_setprio(0);
    }

    u32 pkl[4][2][2];
#pragma unroll
    for (int nt = 0; nt < 2; nt++)
#pragma unroll
      for (int mt = 0; mt < 4; mt++) {
        float p0 = exp2f(accS[mt][nt][0]);
        float p1 = exp2f(accS[mt][nt][1]);
        float p2 = exp2f(accS[mt][nt][2]);
        float p3 = exp2f(accS[mt][nt][3]);
        lsum[nt] += (p0 + p1) + (p2 + p3);
        pkl[mt][nt][0] = cvt_pk_bf16(p0, p1);
        pkl[mt][nt][1] = cvt_pk_bf16(p2, p3);
      }

#pragma unroll
    for (int kf = 0; kf < 2; kf++) {
      bh8 ap[2];
#pragma unroll
      for (int nt = 0; nt < 2; nt++)
        ap[nt] = __builtin_bit_cast(
            bh8, (uint4){pkl[2 * kf][nt][0], pkl[2 * kf][nt][1],
                         pkl[2 * kf + 1][nt][0], pkl[2 * kf + 1][nt][1]});
#pragma unroll
      for (int d = 0; d < 8; d++) {
        bh8 bv = ld8(&lV[16 * d + lr][((4 * kf + lq) ^ (lr & 7)) * 8]);
        __builtin_amdgcn_s_setprio(1);
#pragma unroll
        for (int nt = 0; nt < 2; nt++)
          accO[nt][d] = MFMA16(ap[nt], bv, accO[nt][d]);
        __builtin_amdgcn_s_setprio(0);
      }
    }
  }

#pragma unroll
  for (int nt = 0; nt < 2; nt++) {
    lRed[w][lq][lr] = lsum[nt];
    float lt =
        (lRed[w][0][lr] + lRed[w][1][lr]) + (lRed[w][2][lr] + lRed[w][3][lr]);
    float invl = 1.0f / lt;
    if (lq == 0) lBc[w][lr] = invl;
    float ir[4];
#pragma unroll
    for (int r = 0; r < 4; r++) ir[r] = lBc[w][4 * lq + r];
#pragma unroll
    for (int d = 0; d < 8; d++) {
      int dc = 16 * d + lr;
#pragma unroll
      for (int r = 0; r < 4; r++) {
        int srow = qrow0 + 16 * nt + 4 * lq + r;
        ob[(((size_t)(b * 2048 + srow)) * 16 + h) * 128 + dc] =
            f2bf(accO[nt][d][r] * ir[r]);
      }
    }
  }
}

extern "C" void kernel_launch(void* const* d_in, const int* in_sizes, int n_in,
                              void* d_out, int out_size, void* d_ws, size_t ws_size,
                              hipStream_t stream) {
  const float* x   = (const float*)d_in[0];
  const float* Wq  = (const float*)d_in[1];
  const float* bq  = (const float*)d_in[2];
  const float* Wkv = (const float*)d_in[3];
  const float* bkv = (const float*)d_in[4];
  const float* Wo  = (const float*)d_in[5];
  float* out = (float*)d_out;

  u16* xb    = (u16*)d_ws;          // 4096x2048
  u16* wqb   = xb + 8388608;        // 2048x2048  (wkvb contiguous -> fused W)
  u16* wkvb  = wqb + 4194304;       // 1024x2048
  u16* wob   = wkvb + 2097152;      // 2048x2048
  u16* qbf   = wob + 4194304;       // [b][s][16][128] (roped by rope_kernel)
  u16* kvbf  = qbf + 8388608;       // [b][s][1024]
  u16* vtb   = kvbf + 4194304;      // [b][kh][128][2048] (key-permuted)
  u16* attnb = vtb + 2097152;       // [b][s][16][128]
  // split-K partials (after attnb): opart 67 MB f32, lpart 0.5 MB f32
  float* opart = (float*)(attnb + 4194304);
  float* lpart = opart + (size_t)2 * 2048 * 16 * 128 * 2;
  const size_t need =
      (size_t)(attnb + 4194304 - xb) * 2 +                 // u16 region bytes
      (size_t)2 * 2048 * 16 * 128 * 2 * 4 +                // opart bytes
      (size_t)2 * 2048 * 16 * 2 * 4;                       // lpart bytes
  const bool use_split = ws_size >= need;

  conv4_kernel<<<18432, 256, 0, stream>>>(x, Wq, Wkv, Wo, xb, wqb, wkvb, wob);
  gemm_qkv<<<dim3(24, 32), 256, 0, stream>>>(xb, wqb, bq, bkv, qbf, kvbf);
  rope_kernel<<<20480, 256, 0, stream>>>(qbf, kvbf);
  vtrans_kernel<<<dim3(32, 2, 8), 256, 0, stream>>>(kvbf, vtb);
  if (use_split) {
    attn_split<<<dim3(16, 32, 2), 256, 0, stream>>>(qbf, kvbf, vtb, opart, lpart);
    attn_combine<<<8192, 256, 0, stream>>>(opart, lpart, attnb);
  } else {
    attn_kernel<<<dim3(16, 32), 256, 0, stream>>>(qbf, kvbf, vtb, attnb);
  }
  gemm_bt<<<dim3(16, 32), 256, 0, stream>>>(attnb, wob, out, 4096, 2048, 2048);
}

// Round 6
// 357.822 us; speedup vs baseline: 1.4184x; 1.4087x over previous
//
#include <hip/hip_runtime.h>
#include <math.h>

typedef unsigned short u16;
typedef unsigned int u32;
typedef unsigned short us4 __attribute__((ext_vector_type(4)));
typedef unsigned short us8 __attribute__((ext_vector_type(8)));
typedef short bh8 __attribute__((ext_vector_type(8)));   // 8 bf16 (guide §3)
typedef float f4 __attribute__((ext_vector_type(4)));

#define MFMA16(a, b, c) __builtin_amdgcn_mfma_f32_16x16x32_bf16((a), (b), (c), 0, 0, 0)

__device__ __forceinline__ u16 f2bf(float f) {
  unsigned u = __builtin_bit_cast(unsigned, f);
  u += 0x7FFFu + ((u >> 16) & 1u);   // RNE
  return (u16)(u >> 16);
}
__device__ __forceinline__ float bf2f(u16 h) {
  return __builtin_bit_cast(float, ((unsigned)h) << 16);
}
// gfx950 packed f32->bf16 RNE convert (T12 recipe: no builtin, inline asm)
__device__ __forceinline__ u32 cvt_pk_bf16(float lo, float hi) {
  u32 r;
  asm("v_cvt_pk_bf16_f32 %0, %1, %2" : "=v"(r) : "v"(lo), "v"(hi));
  return r;
}
__device__ __forceinline__ bh8 ld8(const u16* p) {
  return __builtin_bit_cast(bh8, *(const us8*)p);
}
// async global->LDS, 16B per lane. LDS dest = wave-uniform base + lane*16.
__device__ __forceinline__ void gl_lds16(const u16* g, u16* l) {
  __builtin_amdgcn_global_load_lds(
      (const __attribute__((address_space(1))) u32*)g,
      (__attribute__((address_space(3))) u32*)l, 16, 0, 0);
}

// ---------------- fused fp32 -> bf16 (x, Wq, Wkv, Wo) ----------------
__global__ __launch_bounds__(256) void conv4_kernel(const float* __restrict__ x,
                                                    const float* __restrict__ wq,
                                                    const float* __restrict__ wkv,
                                                    const float* __restrict__ wo,
                                                    u16* __restrict__ xb,
                                                    u16* __restrict__ wqb,
                                                    u16* __restrict__ wkvb,
                                                    u16* __restrict__ wob) {
  int i = blockIdx.x * 256 + threadIdx.x;
  const float* in;
  u16* out;
  int j;
  if (i < 2097152) { in = x; out = xb; j = i; }
  else if (i < 3145728) { in = wq; out = wqb; j = i - 2097152; }
  else if (i < 3670016) { in = wkv; out = wkvb; j = i - 3145728; }
  else { in = wo; out = wob; j = i - 3670016; }
  float4 v = ((const float4*)in)[j];
  us4 o;
  o[0] = f2bf(v.x); o[1] = f2bf(v.y); o[2] = f2bf(v.z); o[3] = f2bf(v.w);
  *(us4*)(out + (size_t)j * 4) = o;
}

// ---------------- fused QKV projection (R1-exact; NO epilogue fattening:
// any extra live state here spills the 64-reg accumulator — R3/R4) -------
__global__ __launch_bounds__(256) void gemm_qkv(const u16* __restrict__ A,
                                                const u16* __restrict__ W,
                                                const float* __restrict__ bq,
                                                const float* __restrict__ bkv,
                                                u16* __restrict__ qout,
                                                u16* __restrict__ kvout) {
  const int K = 2048;
  __shared__ __align__(16) u16 lA[128][64];
  __shared__ __align__(16) u16 lB[128][64];
  const int tid = threadIdx.x;
  const int w = tid >> 6, l = tid & 63, lr = l & 15, lq = l >> 4;
  const int wm = w >> 1, wn = w & 1;
  const int rowBase = blockIdx.y * 128, colBase = blockIdx.x * 128;
  const int srow = l >> 3;
  const int scol = ((l & 7) ^ srow) * 8;

  f4 acc[4][4];
#pragma unroll
  for (int i = 0; i < 4; i++)
#pragma unroll
    for (int j = 0; j < 4; j++) acc[i][j] = (f4)0.0f;

  for (int k0 = 0; k0 < K; k0 += 64) {
    __syncthreads();
#pragma unroll
    for (int i = 0; i < 4; i++) {
      int r0 = w * 32 + i * 8;
      int grow = r0 + srow;
      gl_lds16(A + (size_t)(rowBase + grow) * K + k0 + scol, &lA[r0][0]);
      gl_lds16(W + (size_t)(colBase + grow) * K + k0 + scol, &lB[r0][0]);
    }
    __syncthreads();
#pragma unroll
    for (int kk = 0; kk < 64; kk += 32) {
      bh8 af[4], bf[4];
#pragma unroll
      for (int t = 0; t < 4; t++) {
        int c = ((((kk >> 3) + lq) ^ (lr & 7)) * 8);
        af[t] = ld8(&lA[wm * 64 + t * 16 + lr][c]);
        bf[t] = ld8(&lB[wn * 64 + t * 16 + lr][c]);
      }
#pragma unroll
      for (int mt = 0; mt < 4; mt++)
#pragma unroll
        for (int nt = 0; nt < 4; nt++)
          acc[mt][nt] = MFMA16(af[mt], bf[nt], acc[mt][nt]);
    }
  }
#pragma unroll
  for (int mt = 0; mt < 4; mt++) {
#pragma unroll
    for (int nt = 0; nt < 4; nt++) {
      int col = colBase + wn * 64 + nt * 16 + lr;
      float bv = (col < 2048) ? bq[col] : bkv[col - 2048];
#pragma unroll
      for (int r = 0; r < 4; r++) {
        int row = rowBase + wm * 64 + mt * 16 + 4 * lq + r;
        float v = acc[mt][nt][r] + bv;
        if (col < 2048)
          qout[(size_t)row * 2048 + col] = f2bf(v);
        else
          kvout[(size_t)row * 1024 + col - 2048] = f2bf(v);
      }
    }
  }
}

// ---------------- O projection: C = A * W^T (fp32 out) ----------------
__global__ __launch_bounds__(256) void gemm_bt(const u16* __restrict__ A,
                                               const u16* __restrict__ W,
                                               float* __restrict__ outp,
                                               int M, int N, int K) {
  __shared__ __align__(16) u16 lA[128][64];
  __shared__ __align__(16) u16 lB[128][64];
  const int tid = threadIdx.x;
  const int w = tid >> 6, l = tid & 63, lr = l & 15, lq = l >> 4;
  const int wm = w >> 1, wn = w & 1;
  const int rowBase = blockIdx.y * 128, colBase = blockIdx.x * 128;
  const int srow = l >> 3;
  const int scol = ((l & 7) ^ srow) * 8;

  f4 acc[4][4];
#pragma unroll
  for (int i = 0; i < 4; i++)
#pragma unroll
    for (int j = 0; j < 4; j++) acc[i][j] = (f4)0.0f;

  for (int k0 = 0; k0 < K; k0 += 64) {
    __syncthreads();
#pragma unroll
    for (int i = 0; i < 4; i++) {
      int r0 = w * 32 + i * 8;
      int grow = r0 + srow;
      gl_lds16(A + (size_t)(rowBase + grow) * K + k0 + scol, &lA[r0][0]);
      gl_lds16(W + (size_t)(colBase + grow) * K + k0 + scol, &lB[r0][0]);
    }
    __syncthreads();
#pragma unroll
    for (int kk = 0; kk < 64; kk += 32) {
      bh8 af[4], bf[4];
#pragma unroll
      for (int t = 0; t < 4; t++) {
        int c = ((((kk >> 3) + lq) ^ (lr & 7)) * 8);
        af[t] = ld8(&lA[wm * 64 + t * 16 + lr][c]);
        bf[t] = ld8(&lB[wn * 64 + t * 16 + lr][c]);
      }
#pragma unroll
      for (int mt = 0; mt < 4; mt++)
#pragma unroll
        for (int nt = 0; nt < 4; nt++)
          acc[mt][nt] = MFMA16(af[mt], bf[nt], acc[mt][nt]);
    }
  }
#pragma unroll
  for (int mt = 0; mt < 4; mt++) {
#pragma unroll
    for (int nt = 0; nt < 4; nt++) {
      int col = colBase + wn * 64 + nt * 16 + lr;
#pragma unroll
      for (int r = 0; r < 4; r++) {
        int row = rowBase + wm * 64 + mt * 16 + 4 * lq + r;
        outp[(size_t)row * N + col] = acc[mt][nt][r];
      }
    }
  }
}

// ---------------- RoPE in-place on bf16 q and k (R5-exact) ----------------
// Q scaled by 1/sqrt(128) * log2(e): softmax then uses raw exp2.
__global__ __launch_bounds__(256) void rope_kernel(u16* __restrict__ qb,
                                                   u16* __restrict__ kvb) {
  const int NQ = 2 * 2048 * 16 * 64;
  int idx = blockIdx.x * 256 + threadIdx.x;
  u16 *p0, *p1;
  int i, s;
  float sc;
  if (idx < NQ) {
    i = idx & 63;
    int h = (idx >> 6) & 15;
    s = (idx >> 10) & 2047;
    int b = idx >> 21;
    size_t base = (((size_t)(b * 2048 + s)) * 16 + h) * 128;
    p0 = qb + base + i;
    p1 = qb + base + 64 + i;
    sc = 0.12751879522655792f;  // 128^-0.5 * log2(e)
  } else {
    int j = idx - NQ;
    i = j & 63;
    int kh = (j >> 6) & 3;
    s = (j >> 8) & 2047;
    int b = j >> 19;
    size_t base = ((size_t)(b * 2048 + s)) * 1024 + kh * 128;
    p0 = kvb + base + i;
    p1 = kvb + base + 64 + i;
    sc = 1.0f;
  }
  float invf = exp2f(-(float)i * 0.20762050593046012f);
  float ang = (float)s * invf;
  float sn, cs;
  sincosf(ang, &sn, &cs);
  float a1 = bf2f(*p0), a2 = bf2f(*p1);
  *p0 = f2bf((a1 * cs - a2 * sn) * sc);
  *p1 = f2bf((a2 * cs + a1 * sn) * sc);
}

// ---------------- V transpose + key-permute ----------------
__global__ __launch_bounds__(256) void vtrans_kernel(const u16* __restrict__ kvb,
                                                     u16* __restrict__ vtb) {
  __shared__ __align__(16) u16 lT[64][72];
  const int tid = threadIdx.x;
  const int s0 = blockIdx.x * 64, d0 = blockIdx.y * 64;
  const int b = blockIdx.z >> 2, kh = blockIdx.z & 3;
  const u16* src = kvb + ((size_t)b * 2048) * 1024 + 512 + kh * 128;
#pragma unroll
  for (int i = 0; i < 2; i++) {
    int slot = tid + i * 256;
    int sl = slot >> 3, colv = slot & 7;
    *(us8*)&lT[sl][colv * 8] =
        *(const us8*)(src + (size_t)(s0 + sl) * 1024 + d0 + colv * 8);
  }
  __syncthreads();
  u16* dst = vtb + ((size_t)(b * 4 + kh) * 128) * 2048;
#pragma unroll
  for (int i = 0; i < 2; i++) {
    int slot = tid + i * 256;
    int dd = slot >> 3, colv = slot & 7;
    us8 v;
#pragma unroll
    for (int j = 0; j < 8; j++) {
      int p = colv * 8 + j;
      int g = p & 32, q5 = p & 31, lqp = q5 >> 3, jp = q5 & 7;
      int key = g + ((jp < 4) ? (4 * lqp + jp) : (12 + 4 * lqp + jp));
      v[j] = lT[key][dd];
    }
    *(us8*)(dst + (size_t)(d0 + dd) * 2048 + s0 + colv * 8) = v;
  }
}

// ---------------- Flash attention, split-K across blocks (R14) ------------
// R5's split spilled because __launch_bounds__(256,4)'s occupancy GUARANTEE
// makes the compiler split the unified file 64 arch + 64 AGPR -> the ~56
// non-accumulator live values overflow 64 arch regs -> spill loop (same
// mechanism as R3's (512,4)). Fix: (256,2) — baseline's constraint, natural
// ~120-reg unified allocation, no spill — and 120 <= 128 means the HW grants
// 4 waves/SIMD at runtime anyway (occupancy steps at 64/128/256). Grid
// 16x32x2 = 1024 blocks, LDS 34 KB -> 4 blocks/CU. Occupancy hypothesis
// finally gets a clean test.
__global__ __launch_bounds__(256, 2) void attn_split(const u16* __restrict__ qb,
                                                     const u16* __restrict__ kvb,
                                                     const u16* __restrict__ vtb,
                                                     float* __restrict__ opart,
                                                     float* __restrict__ lpart) {
  __shared__ __align__(16) u16 lK[64][128];   // [key][d], block c at c^(key&15)
  __shared__ __align__(16) u16 lV[128][64];   // [d][key'], block c at c^(d&7)
  __shared__ float lRed[4][4][16];            // [wave][lq][lr] epilogue scratch
  const int tid = threadIdx.x;
  const int w = tid >> 6, l = tid & 63, lr = l & 15, lq = l >> 4;
  const int qt = blockIdx.x, hb = blockIdx.y, z = blockIdx.z;
  const int b = hb >> 4, h = hb & 15, kh = h >> 2;
  const u16* kptr = kvb + (size_t)b * 2048 * 1024 + kh * 128;
  const u16* vptr = vtb + (size_t)(b * 4 + kh) * 128 * 2048;
  const int qrow0 = qt * 128 + w * 32;
  const size_t ZO = (size_t)2 * 2048 * 16 * 128;   // opart floats per z
  const size_t ZL = (size_t)2 * 2048 * 16;         // lpart floats per z

  const int ksrow = l >> 4;                    // K staging: 4 rows x 16 blk
  const int vsrow = l >> 3;                    // V staging: 8 rows x 8 blk
  const int vscol = ((l & 7) ^ vsrow) * 8;

  // Q B-fragments: lane holds roped Q[q=qrow0+16nt+lr][d=32kt+8lq+j]
  bh8 qf[2][4];
#pragma unroll
  for (int nt = 0; nt < 2; nt++) {
    const u16* qrow =
        qb + (((size_t)(b * 2048 + qrow0 + 16 * nt + lr)) * 16 + h) * 128;
#pragma unroll
    for (int kt = 0; kt < 4; kt++) qf[nt][kt] = ld8(qrow + kt * 32 + 8 * lq);
  }

  f4 accO[2][8];   // O[q=16nt+4lq+r][d=16dt+lr]
#pragma unroll
  for (int nt = 0; nt < 2; nt++)
#pragma unroll
    for (int d = 0; d < 8; d++) accO[nt][d] = (f4)0.0f;
  float lsum[2] = {0.0f, 0.0f};

  for (int t0 = z * 1024; t0 < z * 1024 + 1024; t0 += 64) {
    __syncthreads();
#pragma unroll
    for (int i = 0; i < 4; i++) {
      {  // K tile
        int r0 = w * 16 + i * 4;
        int grow = r0 + ksrow;
        int gcol = ((l & 15) ^ (grow & 15)) * 8;
        gl_lds16(kptr + (size_t)(t0 + grow) * 1024 + gcol, &lK[r0][0]);
      }
      {  // V^T tile
        int r0 = w * 32 + i * 8;
        int grow = r0 + vsrow;
        gl_lds16(vptr + (size_t)grow * 2048 + t0 + vscol, &lV[r0][0]);
      }
    }
    __syncthreads();

    // S^T = K Q^T (ak reads shared across both nt)
    f4 accS[4][2];
#pragma unroll
    for (int mt = 0; mt < 4; mt++)
#pragma unroll
      for (int nt = 0; nt < 2; nt++) accS[mt][nt] = (f4)0.0f;
#pragma unroll
    for (int kt = 0; kt < 4; kt++) {
      bh8 ak[4];
#pragma unroll
      for (int mt = 0; mt < 4; mt++)
        ak[mt] = ld8(&lK[16 * mt + lr][((4 * kt + lq) ^ lr) * 8]);
      __builtin_amdgcn_s_setprio(1);
#pragma unroll
      for (int mt = 0; mt < 4; mt++)
#pragma unroll
        for (int nt = 0; nt < 2; nt++)
          accS[mt][nt] = MFMA16(ak[mt], qf[nt][kt], accS[mt][nt]);
      __builtin_amdgcn_s_setprio(0);
    }

    // p = exp2(s); packed-RNE convert (v_cvt_pk_bf16_f32); row-sum accum
    u32 pkl[4][2][2];
#pragma unroll
    for (int nt = 0; nt < 2; nt++)
#pragma unroll
      for (int mt = 0; mt < 4; mt++) {
        float p0 = exp2f(accS[mt][nt][0]);
        float p1 = exp2f(accS[mt][nt][1]);
        float p2 = exp2f(accS[mt][nt][2]);
        float p3 = exp2f(accS[mt][nt][3]);
        lsum[nt] += (p0 + p1) + (p2 + p3);
        pkl[mt][nt][0] = cvt_pk_bf16(p0, p1);
        pkl[mt][nt][1] = cvt_pk_bf16(p2, p3);
      }

    // O += P V (A-frag in-lane; bv reads shared across both nt)
#pragma unroll
    for (int kf = 0; kf < 2; kf++) {
      bh8 ap[2];
#pragma unroll
      for (int nt = 0; nt < 2; nt++)
        ap[nt] = __builtin_bit_cast(
            bh8, (uint4){pkl[2 * kf][nt][0], pkl[2 * kf][nt][1],
                         pkl[2 * kf + 1][nt][0], pkl[2 * kf + 1][nt][1]});
#pragma unroll
      for (int d = 0; d < 8; d++) {
        bh8 bv = ld8(&lV[16 * d + lr][((4 * kf + lq) ^ (lr & 7)) * 8]);
        __builtin_amdgcn_s_setprio(1);
#pragma unroll
        for (int nt = 0; nt < 2; nt++)
          accO[nt][d] = MFMA16(ap[nt], bv, accO[nt][d]);
        __builtin_amdgcn_s_setprio(0);
      }
    }
  }

  // epilogue: per-block denom partial + raw accO f32 partials
#pragma unroll
  for (int nt = 0; nt < 2; nt++) {
    lRed[w][lq][lr] = lsum[nt];   // same-wave LDS, in-order per wave
    float lt =
        (lRed[w][0][lr] + lRed[w][1][lr]) + (lRed[w][2][lr] + lRed[w][3][lr]);
    if (lq == 0)
      lpart[z * ZL + ((size_t)(b * 2048 + qrow0 + 16 * nt + lr)) * 16 + h] = lt;
#pragma unroll
    for (int d = 0; d < 8; d++) {
      int dc = 16 * d + lr;
#pragma unroll
      for (int r = 0; r < 4; r++) {
        int srow = qrow0 + 16 * nt + 4 * lq + r;
        opart[z * ZO + (((size_t)(b * 2048 + srow)) * 16 + h) * 128 + dc] =
            accO[nt][d][r];
      }
    }
  }
}

// combine: ob = (O0+O1) / (l0+l1), bf16
__global__ __launch_bounds__(256) void attn_combine(const float* __restrict__ opart,
                                                    const float* __restrict__ lpart,
                                                    u16* __restrict__ ob) {
  const size_t ZO = (size_t)2 * 2048 * 16 * 128;
  const size_t ZL = (size_t)2 * 2048 * 16;
  int t = blockIdx.x * 256 + threadIdx.x;   // [0, 2*2048*16*32)
  int d4 = t & 31;
  int bsh = t >> 5;
  size_t base = (size_t)bsh * 128 + d4 * 4;
  float4 o0 = *(const float4*)(opart + base);
  float4 o1 = *(const float4*)(opart + ZO + base);
  float inv = 1.0f / (lpart[bsh] + lpart[ZL + bsh]);
  us4 o;
  o[0] = f2bf((o0.x + o1.x) * inv);
  o[1] = f2bf((o0.y + o1.y) * inv);
  o[2] = f2bf((o0.z + o1.z) * inv);
  o[3] = f2bf((o0.w + o1.w) * inv);
  *(us4*)(ob + base) = o;
}

// ---------------- single-pass attention (R1-exact fallback) ----------------
__global__ __launch_bounds__(256, 2) void attn_kernel(const u16* __restrict__ qb,
                                                      const u16* __restrict__ kvb,
                                                      const u16* __restrict__ vtb,
                                                      u16* __restrict__ ob) {
  __shared__ __align__(16) u16 lK[64][128];
  __shared__ __align__(16) u16 lV[128][64];
  __shared__ float lRed[4][4][16];
  __shared__ float lBc[4][16];
  const int tid = threadIdx.x;
  const int w = tid >> 6, l = tid & 63, lr = l & 15, lq = l >> 4;
  const int qt = blockIdx.x, hb = blockIdx.y;
  const int b = hb >> 4, h = hb & 15, kh = h >> 2;
  const u16* kptr = kvb + (size_t)b * 2048 * 1024 + kh * 128;
  const u16* vptr = vtb + (size_t)(b * 4 + kh) * 128 * 2048;
  const int qrow0 = qt * 128 + w * 32;

  const int ksrow = l >> 4;
  const int vsrow = l >> 3;
  const int vscol = ((l & 7) ^ vsrow) * 8;

  bh8 qf[2][4];
#pragma unroll
  for (int nt = 0; nt < 2; nt++) {
    const u16* qrow =
        qb + (((size_t)(b * 2048 + qrow0 + 16 * nt + lr)) * 16 + h) * 128;
#pragma unroll
    for (int kt = 0; kt < 4; kt++) qf[nt][kt] = ld8(qrow + kt * 32 + 8 * lq);
  }

  f4 accO[2][8];
#pragma unroll
  for (int nt = 0; nt < 2; nt++)
#pragma unroll
    for (int d = 0; d < 8; d++) accO[nt][d] = (f4)0.0f;
  float lsum[2] = {0.0f, 0.0f};

  for (int t0 = 0; t0 < 2048; t0 += 64) {
    __syncthreads();
#pragma unroll
    for (int i = 0; i < 4; i++) {
      {
        int r0 = w * 16 + i * 4;
        int grow = r0 + ksrow;
        int gcol = ((l & 15) ^ (grow & 15)) * 8;
        gl_lds16(kptr + (size_t)(t0 + grow) * 1024 + gcol, &lK[r0][0]);
      }
      {
        int r0 = w * 32 + i * 8;
        int grow = r0 + vsrow;
        gl_lds16(vptr + (size_t)grow * 2048 + t0 + vscol, &lV[r0][0]);
      }
    }
    __syncthreads();

    f4 accS[4][2];
#pragma unroll
    for (int mt = 0; mt < 4; mt++)
#pragma unroll
      for (int nt = 0; nt < 2; nt++) accS[mt][nt] = (f4)0.0f;
#pragma unroll
    for (int kt = 0; kt < 4; kt++) {
      bh8 ak[4];
#pragma unroll
      for (int mt = 0; mt < 4; mt++)
        ak[mt] = ld8(&lK[16 * mt + lr][((4 * kt + lq) ^ lr) * 8]);
      __builtin_amdgcn_s_setprio(1);
#pragma unroll
      for (int mt = 0; mt < 4; mt++)
#pragma unroll
        for (int nt = 0; nt < 2; nt++)
          accS[mt][nt] = MFMA16(ak[mt], qf[nt][kt], accS[mt][nt]);
      __builtin_amdgcn_s_setprio(0);
    }

    u32 pkl[4][2][2];
#pragma unroll
    for (int nt = 0; nt < 2; nt++)
#pragma unroll
      for (int mt = 0; mt < 4; mt++) {
        float p0 = exp2f(accS[mt][nt][0]);
        float p1 = exp2f(accS[mt][nt][1]);
        float p2 = exp2f(accS[mt][nt][2]);
        float p3 = exp2f(accS[mt][nt][3]);
        lsum[nt] += (p0 + p1) + (p2 + p3);
        pkl[mt][nt][0] = cvt_pk_bf16(p0, p1);
        pkl[mt][nt][1] = cvt_pk_bf16(p2, p3);
      }

#pragma unroll
    for (int kf = 0; kf < 2; kf++) {
      bh8 ap[2];
#pragma unroll
      for (int nt = 0; nt < 2; nt++)
        ap[nt] = __builtin_bit_cast(
            bh8, (uint4){pkl[2 * kf][nt][0], pkl[2 * kf][nt][1],
                         pkl[2 * kf + 1][nt][0], pkl[2 * kf + 1][nt][1]});
#pragma unroll
      for (int d = 0; d < 8; d++) {
        bh8 bv = ld8(&lV[16 * d + lr][((4 * kf + lq) ^ (lr & 7)) * 8]);
        __builtin_amdgcn_s_setprio(1);
#pragma unroll
        for (int nt = 0; nt < 2; nt++)
          accO[nt][d] = MFMA16(ap[nt], bv, accO[nt][d]);
        __builtin_amdgcn_s_setprio(0);
      }
    }
  }

#pragma unroll
  for (int nt = 0; nt < 2; nt++) {
    lRed[w][lq][lr] = lsum[nt];
    float lt =
        (lRed[w][0][lr] + lRed[w][1][lr]) + (lRed[w][2][lr] + lRed[w][3][lr]);
    float invl = 1.0f / lt;
    if (lq == 0) lBc[w][lr] = invl;
    float ir[4];
#pragma unroll
    for (int r = 0; r < 4; r++) ir[r] = lBc[w][4 * lq + r];
#pragma unroll
    for (int d = 0; d < 8; d++) {
      int dc = 16 * d + lr;
#pragma unroll
      for (int r = 0; r < 4; r++) {
        int srow = qrow0 + 16 * nt + 4 * lq + r;
        ob[(((size_t)(b * 2048 + srow)) * 16 + h) * 128 + dc] =
            f2bf(accO[nt][d][r] * ir[r]);
      }
    }
  }
}

extern "C" void kernel_launch(void* const* d_in, const int* in_sizes, int n_in,
                              void* d_out, int out_size, void* d_ws, size_t ws_size,
                              hipStream_t stream) {
  const float* x   = (const float*)d_in[0];
  const float* Wq  = (const float*)d_in[1];
  const float* bq  = (const float*)d_in[2];
  const float* Wkv = (const float*)d_in[3];
  const float* bkv = (const float*)d_in[4];
  const float* Wo  = (const float*)d_in[5];
  float* out = (float*)d_out;

  u16* xb    = (u16*)d_ws;          // 4096x2048
  u16* wqb   = xb + 8388608;        // 2048x2048  (wkvb contiguous -> fused W)
  u16* wkvb  = wqb + 4194304;       // 1024x2048
  u16* wob   = wkvb + 2097152;      // 2048x2048
  u16* qbf   = wob + 4194304;       // [b][s][16][128] (roped by rope_kernel)
  u16* kvbf  = qbf + 8388608;       // [b][s][1024]
  u16* vtb   = kvbf + 4194304;      // [b][kh][128][2048] (key-permuted)
  u16* attnb = vtb + 2097152;       // [b][s][16][128]
  // split-K partials (after attnb): opart 67 MB f32, lpart 0.5 MB f32
  float* opart = (float*)(attnb + 4194304);
  float* lpart = opart + (size_t)2 * 2048 * 16 * 128 * 2;
  const size_t need =
      (size_t)(attnb + 4194304 - xb) * 2 +                 // u16 region bytes
      (size_t)2 * 2048 * 16 * 128 * 2 * 4 +                // opart bytes
      (size_t)2 * 2048 * 16 * 2 * 4;                       // lpart bytes
  const bool use_split = ws_size >= need;

  conv4_kernel<<<18432, 256, 0, stream>>>(x, Wq, Wkv, Wo, xb, wqb, wkvb, wob);
  gemm_qkv<<<dim3(24, 32), 256, 0, stream>>>(xb, wqb, bq, bkv, qbf, kvbf);
  rope_kernel<<<20480, 256, 0, stream>>>(qbf, kvbf);
  vtrans_kernel<<<dim3(32, 2, 8), 256, 0, stream>>>(kvbf, vtb);
  if (use_split) {
    attn_split<<<dim3(16, 32, 2), 256, 0, stream>>>(qbf, kvbf, vtb, opart, lpart);
    attn_combine<<<8192, 256, 0, stream>>>(opart, lpart, attnb);
  } else {
    attn_kernel<<<dim3(16, 32), 256, 0, stream>>>(qbf, kvbf, vtb, attnb);
  }
  gemm_bt<<<dim3(16, 32), 256, 0, stream>>>(attnb, wob, out, 4096, 2048, 2048);
}

// Round 7
// 321.647 us; speedup vs baseline: 1.5780x; 1.1125x over previous
//
#include <hip/hip_runtime.h>
#include <math.h>

typedef unsigned short u16;
typedef unsigned int u32;
typedef unsigned short us4 __attribute__((ext_vector_type(4)));
typedef unsigned short us8 __attribute__((ext_vector_type(8)));
typedef short bh8 __attribute__((ext_vector_type(8)));   // 8 bf16 (guide §3)
typedef float f4 __attribute__((ext_vector_type(4)));

#define MFMA16(a, b, c) __builtin_amdgcn_mfma_f32_16x16x32_bf16((a), (b), (c), 0, 0, 0)

__device__ __forceinline__ u16 f2bf(float f) {
  unsigned u = __builtin_bit_cast(unsigned, f);
  u += 0x7FFFu + ((u >> 16) & 1u);   // RNE
  return (u16)(u >> 16);
}
__device__ __forceinline__ float bf2f(u16 h) {
  return __builtin_bit_cast(float, ((unsigned)h) << 16);
}
// gfx950 packed f32->bf16 RNE convert (T12 recipe: no builtin, inline asm)
__device__ __forceinline__ u32 cvt_pk_bf16(float lo, float hi) {
  u32 r;
  asm("v_cvt_pk_bf16_f32 %0, %1, %2" : "=v"(r) : "v"(lo), "v"(hi));
  return r;
}
__device__ __forceinline__ bh8 ld8(const u16* p) {
  return __builtin_bit_cast(bh8, *(const us8*)p);
}
// async global->LDS, 16B per lane. LDS dest = wave-uniform base + lane*16.
__device__ __forceinline__ void gl_lds16(const u16* g, u16* l) {
  __builtin_amdgcn_global_load_lds(
      (const __attribute__((address_space(1))) u32*)g,
      (__attribute__((address_space(3))) u32*)l, 16, 0, 0);
}

// ---------------- fused fp32 -> bf16 (x, Wq, Wkv, Wo) ----------------
__global__ __launch_bounds__(256) void conv4_kernel(const float* __restrict__ x,
                                                    const float* __restrict__ wq,
                                                    const float* __restrict__ wkv,
                                                    const float* __restrict__ wo,
                                                    u16* __restrict__ xb,
                                                    u16* __restrict__ wqb,
                                                    u16* __restrict__ wkvb,
                                                    u16* __restrict__ wob) {
  int i = blockIdx.x * 256 + threadIdx.x;
  const float* in;
  u16* out;
  int j;
  if (i < 2097152) { in = x; out = xb; j = i; }
  else if (i < 3145728) { in = wq; out = wqb; j = i - 2097152; }
  else if (i < 3670016) { in = wkv; out = wkvb; j = i - 3145728; }
  else { in = wo; out = wob; j = i - 3670016; }
  float4 v = ((const float4*)in)[j];
  us4 o;
  o[0] = f2bf(v.x); o[1] = f2bf(v.y); o[2] = f2bf(v.z); o[3] = f2bf(v.w);
  *(us4*)(out + (size_t)j * 4) = o;
}

// ---------------- fused QKV projection, dbuf prefetch K-loop (R15) --------
// Old: sync; stage; sync(=vmcnt(0) drain right after issue); compute -> full
// L2 latency exposed x32 K-steps (m233's 2-phase stall). New: issue tile
// t+1's 8 gl_lds16 at iter top into buf^1, compute tile t, ONE
// __syncthreads at bottom (its vmcnt(0)+lgkmcnt(0) is exactly the needed
// wait; loads had a full compute phase to land). Writes to buf^1 are
// protected by the previous bottom barrier. MFMA order unchanged.
__global__ __launch_bounds__(256) void gemm_qkv(const u16* __restrict__ A,
                                                const u16* __restrict__ W,
                                                const float* __restrict__ bq,
                                                const float* __restrict__ bkv,
                                                u16* __restrict__ qout,
                                                u16* __restrict__ kvout) {
  const int K = 2048;
  __shared__ __align__(16) u16 lA[2][128][64];
  __shared__ __align__(16) u16 lB[2][128][64];
  const int tid = threadIdx.x;
  const int w = tid >> 6, l = tid & 63, lr = l & 15, lq = l >> 4;
  const int wm = w >> 1, wn = w & 1;
  const int rowBase = blockIdx.y * 128, colBase = blockIdx.x * 128;
  const int srow = l >> 3;
  const int scol = ((l & 7) ^ srow) * 8;

  f4 acc[4][4];
#pragma unroll
  for (int i = 0; i < 4; i++)
#pragma unroll
    for (int j = 0; j < 4; j++) acc[i][j] = (f4)0.0f;

  auto STAGE = [&](int b, int k0) {
#pragma unroll
    for (int i = 0; i < 4; i++) {
      int r0 = w * 32 + i * 8;
      int grow = r0 + srow;
      gl_lds16(A + (size_t)(rowBase + grow) * K + k0 + scol, &lA[b][r0][0]);
      gl_lds16(W + (size_t)(colBase + grow) * K + k0 + scol, &lB[b][r0][0]);
    }
  };

  STAGE(0, 0);
  __syncthreads();
  for (int t = 0; t < 32; t++) {
    if (t + 1 < 32) STAGE((t + 1) & 1, (t + 1) * 64);
    __builtin_amdgcn_sched_barrier(0);   // keep stage issue ahead of ds_reads
    const u16(*pA)[64] = lA[t & 1];
    const u16(*pB)[64] = lB[t & 1];
#pragma unroll
    for (int kk = 0; kk < 64; kk += 32) {
      bh8 af[4], bf[4];
#pragma unroll
      for (int q = 0; q < 4; q++) {
        int c = ((((kk >> 3) + lq) ^ (lr & 7)) * 8);
        af[q] = ld8(&pA[wm * 64 + q * 16 + lr][c]);
        bf[q] = ld8(&pB[wn * 64 + q * 16 + lr][c]);
      }
#pragma unroll
      for (int mt = 0; mt < 4; mt++)
#pragma unroll
        for (int nt = 0; nt < 4; nt++)
          acc[mt][nt] = MFMA16(af[mt], bf[nt], acc[mt][nt]);
    }
    __syncthreads();   // drains vmcnt(0)+lgkmcnt(0): t+1 landed, reads done
  }
#pragma unroll
  for (int mt = 0; mt < 4; mt++) {
#pragma unroll
    for (int nt = 0; nt < 4; nt++) {
      int col = colBase + wn * 64 + nt * 16 + lr;
      float bv = (col < 2048) ? bq[col] : bkv[col - 2048];
#pragma unroll
      for (int r = 0; r < 4; r++) {
        int row = rowBase + wm * 64 + mt * 16 + 4 * lq + r;
        float v = acc[mt][nt][r] + bv;
        if (col < 2048)
          qout[(size_t)row * 2048 + col] = f2bf(v);
        else
          kvout[(size_t)row * 1024 + col - 2048] = f2bf(v);
      }
    }
  }
}

// ---------------- O projection: C = A * W^T (fp32 out), same R15 loop -----
__global__ __launch_bounds__(256) void gemm_bt(const u16* __restrict__ A,
                                               const u16* __restrict__ W,
                                               float* __restrict__ outp,
                                               int M, int N, int K) {
  __shared__ __align__(16) u16 lA[2][128][64];
  __shared__ __align__(16) u16 lB[2][128][64];
  const int tid = threadIdx.x;
  const int w = tid >> 6, l = tid & 63, lr = l & 15, lq = l >> 4;
  const int wm = w >> 1, wn = w & 1;
  const int rowBase = blockIdx.y * 128, colBase = blockIdx.x * 128;
  const int srow = l >> 3;
  const int scol = ((l & 7) ^ srow) * 8;

  f4 acc[4][4];
#pragma unroll
  for (int i = 0; i < 4; i++)
#pragma unroll
    for (int j = 0; j < 4; j++) acc[i][j] = (f4)0.0f;

  auto STAGE = [&](int b, int k0) {
#pragma unroll
    for (int i = 0; i < 4; i++) {
      int r0 = w * 32 + i * 8;
      int grow = r0 + srow;
      gl_lds16(A + (size_t)(rowBase + grow) * K + k0 + scol, &lA[b][r0][0]);
      gl_lds16(W + (size_t)(colBase + grow) * K + k0 + scol, &lB[b][r0][0]);
    }
  };

  const int NT = K >> 6;
  STAGE(0, 0);
  __syncthreads();
  for (int t = 0; t < NT; t++) {
    if (t + 1 < NT) STAGE((t + 1) & 1, (t + 1) * 64);
    __builtin_amdgcn_sched_barrier(0);
    const u16(*pA)[64] = lA[t & 1];
    const u16(*pB)[64] = lB[t & 1];
#pragma unroll
    for (int kk = 0; kk < 64; kk += 32) {
      bh8 af[4], bf[4];
#pragma unroll
      for (int q = 0; q < 4; q++) {
        int c = ((((kk >> 3) + lq) ^ (lr & 7)) * 8);
        af[q] = ld8(&pA[wm * 64 + q * 16 + lr][c]);
        bf[q] = ld8(&pB[wn * 64 + q * 16 + lr][c]);
      }
#pragma unroll
      for (int mt = 0; mt < 4; mt++)
#pragma unroll
        for (int nt = 0; nt < 4; nt++)
          acc[mt][nt] = MFMA16(af[mt], bf[nt], acc[mt][nt]);
    }
    __syncthreads();
  }
#pragma unroll
  for (int mt = 0; mt < 4; mt++) {
#pragma unroll
    for (int nt = 0; nt < 4; nt++) {
      int col = colBase + wn * 64 + nt * 16 + lr;
#pragma unroll
      for (int r = 0; r < 4; r++) {
        int row = rowBase + wm * 64 + mt * 16 + 4 * lq + r;
        outp[(size_t)row * N + col] = acc[mt][nt][r];
      }
    }
  }
}

// ---------------- RoPE in-place on bf16 q and k (R5-exact) ----------------
// Q scaled by 1/sqrt(128) * log2(e): softmax then uses raw exp2.
__global__ __launch_bounds__(256) void rope_kernel(u16* __restrict__ qb,
                                                   u16* __restrict__ kvb) {
  const int NQ = 2 * 2048 * 16 * 64;
  int idx = blockIdx.x * 256 + threadIdx.x;
  u16 *p0, *p1;
  int i, s;
  float sc;
  if (idx < NQ) {
    i = idx & 63;
    int h = (idx >> 6) & 15;
    s = (idx >> 10) & 2047;
    int b = idx >> 21;
    size_t base = (((size_t)(b * 2048 + s)) * 16 + h) * 128;
    p0 = qb + base + i;
    p1 = qb + base + 64 + i;
    sc = 0.12751879522655792f;  // 128^-0.5 * log2(e)
  } else {
    int j = idx - NQ;
    i = j & 63;
    int kh = (j >> 6) & 3;
    s = (j >> 8) & 2047;
    int b = j >> 19;
    size_t base = ((size_t)(b * 2048 + s)) * 1024 + kh * 128;
    p0 = kvb + base + i;
    p1 = kvb + base + 64 + i;
    sc = 1.0f;
  }
  float invf = exp2f(-(float)i * 0.20762050593046012f);
  float ang = (float)s * invf;
  float sn, cs;
  sincosf(ang, &sn, &cs);
  float a1 = bf2f(*p0), a2 = bf2f(*p1);
  *p0 = f2bf((a1 * cs - a2 * sn) * sc);
  *p1 = f2bf((a2 * cs + a1 * sn) * sc);
}

// ---------------- V transpose + key-permute ----------------
__global__ __launch_bounds__(256) void vtrans_kernel(const u16* __restrict__ kvb,
                                                     u16* __restrict__ vtb) {
  __shared__ __align__(16) u16 lT[64][72];
  const int tid = threadIdx.x;
  const int s0 = blockIdx.x * 64, d0 = blockIdx.y * 64;
  const int b = blockIdx.z >> 2, kh = blockIdx.z & 3;
  const u16* src = kvb + ((size_t)b * 2048) * 1024 + 512 + kh * 128;
#pragma unroll
  for (int i = 0; i < 2; i++) {
    int slot = tid + i * 256;
    int sl = slot >> 3, colv = slot & 7;
    *(us8*)&lT[sl][colv * 8] =
        *(const us8*)(src + (size_t)(s0 + sl) * 1024 + d0 + colv * 8);
  }
  __syncthreads();
  u16* dst = vtb + ((size_t)(b * 4 + kh) * 128) * 2048;
#pragma unroll
  for (int i = 0; i < 2; i++) {
    int slot = tid + i * 256;
    int dd = slot >> 3, colv = slot & 7;
    us8 v;
#pragma unroll
    for (int j = 0; j < 8; j++) {
      int p = colv * 8 + j;
      int g = p & 32, q5 = p & 31, lqp = q5 >> 3, jp = q5 & 7;
      int key = g + ((jp < 4) ? (4 * lqp + jp) : (12 + 4 * lqp + jp));
      v[j] = lT[key][dd];
    }
    *(us8*)(dst + (size_t)(d0 + dd) * 2048 + s0 + colv * 8) = v;
  }
}

// ---------------- Flash attention (R1-exact; plateau accepted) ------------
// R1 VALU-shave null, R2 prefetch -3%, R3/R5 split-K spilled, R6 split-K
// clean but no overlap: total regs (~124 arch + 64 AGPR = 188) cap HW at
// 2 waves/SIMD regardless of grid. ~719 TF effective = the 2-wave serial-
// chain plateau of this structure. Leave as-is.
__global__ __launch_bounds__(256, 2) void attn_kernel(const u16* __restrict__ qb,
                                                      const u16* __restrict__ kvb,
                                                      const u16* __restrict__ vtb,
                                                      u16* __restrict__ ob) {
  __shared__ __align__(16) u16 lK[64][128];   // [key][d], block c at c^(key&15)
  __shared__ __align__(16) u16 lV[128][64];   // [d][key'], block c at c^(d&7)
  __shared__ float lRed[4][4][16];            // [wave][lq][lr] epilogue scratch
  __shared__ float lBc[4][16];                // [wave][row] epilogue broadcast
  const int tid = threadIdx.x;
  const int w = tid >> 6, l = tid & 63, lr = l & 15, lq = l >> 4;
  const int qt = blockIdx.x, hb = blockIdx.y;
  const int b = hb >> 4, h = hb & 15, kh = h >> 2;
  const u16* kptr = kvb + (size_t)b * 2048 * 1024 + kh * 128;
  const u16* vptr = vtb + (size_t)(b * 4 + kh) * 128 * 2048;
  const int qrow0 = qt * 128 + w * 32;

  const int ksrow = l >> 4;                    // K staging: 4 rows x 16 blk
  const int vsrow = l >> 3;                    // V staging: 8 rows x 8 blk
  const int vscol = ((l & 7) ^ vsrow) * 8;

  // Q B-fragments: lane holds roped Q[q=qrow0+16nt+lr][d=32kt+8lq+j]
  bh8 qf[2][4];
#pragma unroll
  for (int nt = 0; nt < 2; nt++) {
    const u16* qrow =
        qb + (((size_t)(b * 2048 + qrow0 + 16 * nt + lr)) * 16 + h) * 128;
#pragma unroll
    for (int kt = 0; kt < 4; kt++) qf[nt][kt] = ld8(qrow + kt * 32 + 8 * lq);
  }

  f4 accO[2][8];   // O[q=16nt+4lq+r][d=16dt+lr]
#pragma unroll
  for (int nt = 0; nt < 2; nt++)
#pragma unroll
    for (int d = 0; d < 8; d++) accO[nt][d] = (f4)0.0f;
  float lsum[2] = {0.0f, 0.0f};

  for (int t0 = 0; t0 < 2048; t0 += 64) {
    __syncthreads();
#pragma unroll
    for (int i = 0; i < 4; i++) {
      {  // K tile
        int r0 = w * 16 + i * 4;
        int grow = r0 + ksrow;
        int gcol = ((l & 15) ^ (grow & 15)) * 8;
        gl_lds16(kptr + (size_t)(t0 + grow) * 1024 + gcol, &lK[r0][0]);
      }
      {  // V^T tile
        int r0 = w * 32 + i * 8;
        int grow = r0 + vsrow;
        gl_lds16(vptr + (size_t)grow * 2048 + t0 + vscol, &lV[r0][0]);
      }
    }
    __syncthreads();

    // S^T = K Q^T (ak reads shared across both nt)
    f4 accS[4][2];
#pragma unroll
    for (int mt = 0; mt < 4; mt++)
#pragma unroll
      for (int nt = 0; nt < 2; nt++) accS[mt][nt] = (f4)0.0f;
#pragma unroll
    for (int kt = 0; kt < 4; kt++) {
      bh8 ak[4];
#pragma unroll
      for (int mt = 0; mt < 4; mt++)
        ak[mt] = ld8(&lK[16 * mt + lr][((4 * kt + lq) ^ lr) * 8]);
      __builtin_amdgcn_s_setprio(1);
#pragma unroll
      for (int mt = 0; mt < 4; mt++)
#pragma unroll
        for (int nt = 0; nt < 2; nt++)
          accS[mt][nt] = MFMA16(ak[mt], qf[nt][kt], accS[mt][nt]);
      __builtin_amdgcn_s_setprio(0);
    }

    // p = exp2(s); packed-RNE convert (v_cvt_pk_bf16_f32); row-sum accum
    u32 pkl[4][2][2];
#pragma unroll
    for (int nt = 0; nt < 2; nt++)
#pragma unroll
      for (int mt = 0; mt < 4; mt++) {
        float p0 = exp2f(accS[mt][nt][0]);
        float p1 = exp2f(accS[mt][nt][1]);
        float p2 = exp2f(accS[mt][nt][2]);
        float p3 = exp2f(accS[mt][nt][3]);
        lsum[nt] += (p0 + p1) + (p2 + p3);
        pkl[mt][nt][0] = cvt_pk_bf16(p0, p1);
        pkl[mt][nt][1] = cvt_pk_bf16(p2, p3);
      }

    // O += P V (A-frag in-lane; bv reads shared across both nt)
#pragma unroll
    for (int kf = 0; kf < 2; kf++) {
      bh8 ap[2];
#pragma unroll
      for (int nt = 0; nt < 2; nt++)
        ap[nt] = __builtin_bit_cast(
            bh8, (uint4){pkl[2 * kf][nt][0], pkl[2 * kf][nt][1],
                         pkl[2 * kf + 1][nt][0], pkl[2 * kf + 1][nt][1]});
#pragma unroll
      for (int d = 0; d < 8; d++) {
        bh8 bv = ld8(&lV[16 * d + lr][((4 * kf + lq) ^ (lr & 7)) * 8]);
        __builtin_amdgcn_s_setprio(1);
#pragma unroll
        for (int nt = 0; nt < 2; nt++)
          accO[nt][d] = MFMA16(ap[nt], bv, accO[nt][d]);
        __builtin_amdgcn_s_setprio(0);
      }
    }
  }

  // epilogue: reduce row sums across lq, O /= l, write [b][s][h][d] bf16
#pragma unroll
  for (int nt = 0; nt < 2; nt++) {
    lRed[w][lq][lr] = lsum[nt];   // same-wave LDS, in-order per wave
    float lt =
        (lRed[w][0][lr] + lRed[w][1][lr]) + (lRed[w][2][lr] + lRed[w][3][lr]);
    float invl = 1.0f / lt;
    if (lq == 0) lBc[w][lr] = invl;
    float ir[4];
#pragma unroll
    for (int r = 0; r < 4; r++) ir[r] = lBc[w][4 * lq + r];
#pragma unroll
    for (int d = 0; d < 8; d++) {
      int dc = 16 * d + lr;
#pragma unroll
      for (int r = 0; r < 4; r++) {
        int srow = qrow0 + 16 * nt + 4 * lq + r;
        ob[(((size_t)(b * 2048 + srow)) * 16 + h) * 128 + dc] =
            f2bf(accO[nt][d][r] * ir[r]);
      }
    }
  }
}

extern "C" void kernel_launch(void* const* d_in, const int* in_sizes, int n_in,
                              void* d_out, int out_size, void* d_ws, size_t ws_size,
                              hipStream_t stream) {
  const float* x   = (const float*)d_in[0];
  const float* Wq  = (const float*)d_in[1];
  const float* bq  = (const float*)d_in[2];
  const float* Wkv = (const float*)d_in[3];
  const float* bkv = (const float*)d_in[4];
  const float* Wo  = (const float*)d_in[5];
  float* out = (float*)d_out;

  u16* xb    = (u16*)d_ws;          // 4096x2048
  u16* wqb   = xb + 8388608;        // 2048x2048  (wkvb contiguous -> fused W)
  u16* wkvb  = wqb + 4194304;       // 1024x2048
  u16* wob   = wkvb + 2097152;      // 2048x2048
  u16* qbf   = wob + 4194304;       // [b][s][16][128] (roped by rope_kernel)
  u16* kvbf  = qbf + 8388608;       // [b][s][1024]
  u16* vtb   = kvbf + 4194304;      // [b][kh][128][2048] (key-permuted)
  u16* attnb = vtb + 2097152;       // [b][s][16][128]

  conv4_kernel<<<18432, 256, 0, stream>>>(x, Wq, Wkv, Wo, xb, wqb, wkvb, wob);
  gemm_qkv<<<dim3(24, 32), 256, 0, stream>>>(xb, wqb, bq, bkv, qbf, kvbf);
  rope_kernel<<<20480, 256, 0, stream>>>(qbf, kvbf);
  vtrans_kernel<<<dim3(32, 2, 8), 256, 0, stream>>>(kvbf, vtb);
  attn_kernel<<<dim3(16, 32), 256, 0, stream>>>(qbf, kvbf, vtb, attnb);
  gemm_bt<<<dim3(16, 32), 256, 0, stream>>>(attnb, wob, out, 4096, 2048, 2048);
}